// Round 1
// baseline (126.454 us; speedup 1.0000x reference)
//
#include <hip/hip_runtime.h>

// Problem constants
#define B 32
#define S 2048
#define HDIM 1024
#define CCH 32                   // chunks per batch in flash pass
#define INV_SQRT_H 0.03125f      // 1/sqrt(1024)

// Workspace layout (float offsets). Total ~4.9 MB.
#define WS_Q    0                        // [B][H]      q = dec@Wq^T + bq
#define WS_QW   (32*1024)                // [B][H]      qW = q@Wk
#define WS_QB   (64*1024)                // [B]         (q . bk) * INV_SQRT_H
#define WS_E    (WS_QB + 64)             // [B][S]      scaled energies
#define WS_ML   (WS_E + 32*2048)         // [B*CCH][2]  per-chunk (m, l)
#define WS_ACC  (WS_ML + 32*CCH*2)       // [B*CCH][H]  per-chunk partial acc
#define WS_C    (WS_ACC + 32*CCH*1024)   // [B][H]      c_hat = softmax-weighted enc

__device__ __forceinline__ float dot4(float4 a, float4 b) {
    return a.x*b.x + a.y*b.y + a.z*b.z + a.w*b.w;
}

__device__ __forceinline__ float wave_reduce_add(float v) {
#pragma unroll
    for (int off = 32; off >= 1; off >>= 1) v += __shfl_xor(v, off);
    return v;
}

// ---------------------------------------------------------------------------
// P1: q[b,o] = dec[b,:] . Wq[o,:] + bq[o]
// grid 512 = 32 b * 16 o-chunks of 64; 256 threads (4 waves, 16 dots each)
__global__ __launch_bounds__(256) void k_q(const float* __restrict__ dec,
                                           const float* __restrict__ Wq,
                                           const float* __restrict__ bq,
                                           float* __restrict__ ws) {
    int b = blockIdx.x >> 4;
    int oc = blockIdx.x & 15;
    int wave = threadIdx.x >> 6, lane = threadIdx.x & 63;
    const float4* dec4 = (const float4*)(dec + (size_t)b * HDIM);
    float4 d0 = dec4[lane], d1 = dec4[64 + lane], d2 = dec4[128 + lane], d3 = dec4[192 + lane];
#pragma unroll 4
    for (int i = 0; i < 16; ++i) {
        int o = oc * 64 + wave * 16 + i;
        const float4* w4 = (const float4*)(Wq + (size_t)o * HDIM);
        float4 a0 = w4[lane], a1 = w4[64 + lane], a2 = w4[128 + lane], a3 = w4[192 + lane];
        float d = dot4(a0, d0) + dot4(a1, d1) + dot4(a2, d2) + dot4(a3, d3);
        d = wave_reduce_add(d);
        if (lane == 0) ws[WS_Q + b * HDIM + o] = d + bq[o];
    }
}

// ---------------------------------------------------------------------------
// P2: qW[b,h] = sum_o q[b,o] * Wk[o,h];  qb_s[b] = (q[b,:] . bk) * INV_SQRT_H
// grid 512 = 32 b * 16 h-chunks of 64; 256 threads = 64 cols x 4 o-chunks
__global__ __launch_bounds__(256) void k_qw(const float* __restrict__ Wk,
                                            const float* __restrict__ bk,
                                            float* __restrict__ ws) {
    int b = blockIdx.x >> 4;
    int hc = blockIdx.x & 15;
    int t = threadIdx.x;
    int col = hc * 64 + (t & 63);
    int oc = t >> 6;
    const float* q = ws + WS_Q + b * HDIM;
    float acc = 0.f;
#pragma unroll 4
    for (int o = oc * 256; o < oc * 256 + 256; ++o)
        acc += q[o] * Wk[(size_t)o * HDIM + col];
    __shared__ float lds[4][64];
    lds[oc][t & 63] = acc;
    __syncthreads();
    if (t < 64) {
        float ssum = lds[0][t] + lds[1][t] + lds[2][t] + lds[3][t];
        ws[WS_QW + b * HDIM + hc * 64 + t] = ssum;
    }
    if (hc == 0 && t < 64) {
        const float4* q4 = (const float4*)q;
        const float4* bk4 = (const float4*)bk;
        float s2 = 0.f;
#pragma unroll
        for (int c = 0; c < 4; ++c) s2 += dot4(q4[64 * c + t], bk4[64 * c + t]);
        s2 = wave_reduce_add(s2);
        if (t == 0) ws[WS_QB + b] = s2 * INV_SQRT_H;
    }
}

// ---------------------------------------------------------------------------
// F1: flash pass over enc. Each block: one (b, chunk) of 64 rows; 4 waves x 16 rows.
// Produces ws_e (scaled energies), per-chunk (m, l, acc[H]).
__global__ __launch_bounds__(256) void k_flash(const float* __restrict__ enc,
                                               float* __restrict__ ws) {
    int b = blockIdx.x >> 5;      // / CCH
    int ch = blockIdx.x & (CCH - 1);
    int wave = threadIdx.x >> 6, lane = threadIdx.x & 63;

    const float4* qw4 = (const float4*)(ws + WS_QW + b * HDIM);
    float4 w0 = qw4[lane], w1 = qw4[64 + lane], w2 = qw4[128 + lane], w3 = qw4[192 + lane];
    float qbs = ws[WS_QB + b];

    float m_run = -1e30f, l_run = 0.f;
    float4 a0 = {0, 0, 0, 0}, a1 = a0, a2 = a0, a3 = a0;

    int s0 = ch * 64 + wave * 16;
    for (int i = 0; i < 16; ++i) {
        int s = s0 + i;
        const float4* r4 = (const float4*)(enc + ((size_t)(b * S + s)) * HDIM);
        float4 e0 = r4[lane], e1 = r4[64 + lane], e2 = r4[128 + lane], e3 = r4[192 + lane];
        float d = dot4(e0, w0) + dot4(e1, w1) + dot4(e2, w2) + dot4(e3, w3);
        d = wave_reduce_add(d);
        float e = d * INV_SQRT_H + qbs;
        if (lane == 0) ws[WS_E + b * S + s] = e;
        float mn = fmaxf(m_run, e);
        float p = __expf(e - mn);
        float f = __expf(m_run - mn);   // == 1 when max unchanged; 0 on first iter
        l_run = l_run * f + p;
        a0.x = a0.x * f + p * e0.x; a0.y = a0.y * f + p * e0.y;
        a0.z = a0.z * f + p * e0.z; a0.w = a0.w * f + p * e0.w;
        a1.x = a1.x * f + p * e1.x; a1.y = a1.y * f + p * e1.y;
        a1.z = a1.z * f + p * e1.z; a1.w = a1.w * f + p * e1.w;
        a2.x = a2.x * f + p * e2.x; a2.y = a2.y * f + p * e2.y;
        a2.z = a2.z * f + p * e2.z; a2.w = a2.w * f + p * e2.w;
        a3.x = a3.x * f + p * e3.x; a3.y = a3.y * f + p * e3.y;
        a3.z = a3.z * f + p * e3.z; a3.w = a3.w * f + p * e3.w;
        m_run = mn;
    }

    // Block combine: 4 waves -> one (m, l, acc[H]) partial
    __shared__ float lacc[4][HDIM];
    __shared__ float lml[4][2];
    float4* la4 = (float4*)lacc[wave];
    la4[lane] = a0; la4[64 + lane] = a1; la4[128 + lane] = a2; la4[192 + lane] = a3;
    if (lane == 0) { lml[wave][0] = m_run; lml[wave][1] = l_run; }
    __syncthreads();

    int t = threadIdx.x;   // 256 threads, each one float4 (h = 4t..4t+3)
    float m0 = lml[0][0], m1 = lml[1][0], m2 = lml[2][0], m3 = lml[3][0];
    float mb = fmaxf(fmaxf(m0, m1), fmaxf(m2, m3));
    float f0 = __expf(m0 - mb), f1 = __expf(m1 - mb), f2 = __expf(m2 - mb), f3 = __expf(m3 - mb);
    float lb = lml[0][1] * f0 + lml[1][1] * f1 + lml[2][1] * f2 + lml[3][1] * f3;
    float4 c0 = ((float4*)lacc[0])[t];
    float4 c1 = ((float4*)lacc[1])[t];
    float4 c2 = ((float4*)lacc[2])[t];
    float4 c3 = ((float4*)lacc[3])[t];
    float4 cc;
    cc.x = f0 * c0.x + f1 * c1.x + f2 * c2.x + f3 * c3.x;
    cc.y = f0 * c0.y + f1 * c1.y + f2 * c2.y + f3 * c3.y;
    cc.z = f0 * c0.z + f1 * c1.z + f2 * c2.z + f3 * c3.z;
    cc.w = f0 * c0.w + f1 * c1.w + f2 * c2.w + f3 * c3.w;
    ((float4*)(ws + WS_ACC))[(size_t)(b * CCH + ch) * 256 + t] = cc;
    if (t == 0) {
        ws[WS_ML + (b * CCH + ch) * 2 + 0] = mb;
        ws[WS_ML + (b * CCH + ch) * 2 + 1] = lb;
    }
}

// ---------------------------------------------------------------------------
// F2: blocks 0..31: c_hat[b,:] = sum_i exp(m_i-mg) acc_i / lg
//     blocks 32..287: attn[b,s] = exp(e - mg)/lg  -> out[B*H + b*S + s]
__global__ __launch_bounds__(256) void k_combine(float* __restrict__ ws,
                                                 float* __restrict__ out) {
    if (blockIdx.x < 32) {
        int b = blockIdx.x;
        int t = threadIdx.x;
        const float* ml = ws + WS_ML + b * CCH * 2;
        float mg = -1e30f;
#pragma unroll
        for (int i = 0; i < CCH; ++i) mg = fmaxf(mg, ml[2 * i]);
        float lg = 0.f;
#pragma unroll
        for (int i = 0; i < CCH; ++i) lg += ml[2 * i + 1] * __expf(ml[2 * i] - mg);
        float inv_lg = 1.f / lg;
        const float4* acc4 = ((const float4*)(ws + WS_ACC)) + (size_t)b * CCH * 256;
        float4 c = {0, 0, 0, 0};
#pragma unroll 4
        for (int i = 0; i < CCH; ++i) {
            float f = __expf(ml[2 * i] - mg) * inv_lg;
            float4 a = acc4[(size_t)i * 256 + t];
            c.x += f * a.x; c.y += f * a.y; c.z += f * a.z; c.w += f * a.w;
        }
        ((float4*)(ws + WS_C))[b * 256 + t] = c;
    } else {
        int gt = (blockIdx.x - 32) * 256 + threadIdx.x;   // 0..65535 = b*S + s
        int b = gt >> 11;
        const float* ml = ws + WS_ML + b * CCH * 2;
        float mg = -1e30f;
#pragma unroll
        for (int i = 0; i < CCH; ++i) mg = fmaxf(mg, ml[2 * i]);
        float lg = 0.f;
#pragma unroll
        for (int i = 0; i < CCH; ++i) lg += ml[2 * i + 1] * __expf(ml[2 * i] - mg);
        float e = ws[WS_E + gt];
        out[B * HDIM + gt] = __expf(e - mg) / lg;
    }
}

// ---------------------------------------------------------------------------
// F3: context[b,o] = c_hat[b,:] . Wv[o,:] + bv[o];  out0 = gamma*tanh(alpha*ctx)+beta
__global__ __launch_bounds__(256) void k_out(const float* __restrict__ Wv,
                                             const float* __restrict__ bv,
                                             const float* __restrict__ alpha,
                                             const float* __restrict__ gamma,
                                             const float* __restrict__ beta,
                                             const float* __restrict__ ws,
                                             float* __restrict__ out) {
    int b = blockIdx.x >> 4;
    int oc = blockIdx.x & 15;
    int wave = threadIdx.x >> 6, lane = threadIdx.x & 63;
    const float4* c4 = (const float4*)(ws + WS_C + b * HDIM);
    float4 d0 = c4[lane], d1 = c4[64 + lane], d2 = c4[128 + lane], d3 = c4[192 + lane];
    float al = alpha[0];
#pragma unroll 4
    for (int i = 0; i < 16; ++i) {
        int o = oc * 64 + wave * 16 + i;
        const float4* w4 = (const float4*)(Wv + (size_t)o * HDIM);
        float4 a0 = w4[lane], a1 = w4[64 + lane], a2 = w4[128 + lane], a3 = w4[192 + lane];
        float d = dot4(a0, d0) + dot4(a1, d1) + dot4(a2, d2) + dot4(a3, d3);
        d = wave_reduce_add(d);
        if (lane == 0) {
            float y = d + bv[o];
            out[b * HDIM + o] = gamma[o] * tanhf(al * y) + beta[o];
        }
    }
}

// ---------------------------------------------------------------------------
extern "C" void kernel_launch(void* const* d_in, const int* in_sizes, int n_in,
                              void* d_out, int out_size, void* d_ws, size_t ws_size,
                              hipStream_t stream) {
    const float* dec   = (const float*)d_in[0];
    const float* enc   = (const float*)d_in[1];
    const float* Wq    = (const float*)d_in[2];
    const float* bq    = (const float*)d_in[3];
    const float* Wk    = (const float*)d_in[4];
    const float* bk    = (const float*)d_in[5];
    const float* Wv    = (const float*)d_in[6];
    const float* bv    = (const float*)d_in[7];
    const float* alpha = (const float*)d_in[8];
    const float* gamma = (const float*)d_in[9];
    const float* beta  = (const float*)d_in[10];
    float* out = (float*)d_out;
    float* ws  = (float*)d_ws;

    hipLaunchKernelGGL(k_q,       dim3(512),  dim3(256), 0, stream, dec, Wq, bq, ws);
    hipLaunchKernelGGL(k_qw,      dim3(512),  dim3(256), 0, stream, Wk, bk, ws);
    hipLaunchKernelGGL(k_flash,   dim3(1024), dim3(256), 0, stream, enc, ws);
    hipLaunchKernelGGL(k_combine, dim3(288),  dim3(256), 0, stream, ws, out);
    hipLaunchKernelGGL(k_out,     dim3(512),  dim3(256), 0, stream, Wv, bv, alpha, gamma, beta, ws, out);
}